// Round 16
// baseline (308.610 us; speedup 1.0000x reference)
//
#include <hip/hip_runtime.h>
#include <hip/hip_bf16.h>
#include <stdint.h>

typedef __bf16 bf16_t;
typedef __bf16 bf16x8 __attribute__((ext_vector_type(8)));
typedef float f32x4 __attribute__((ext_vector_type(4)));

#define L2E 1.44269504088896340736f

static __device__ __forceinline__ f32x4 mfma16(bf16x8 a, bf16x8 b, f32x4 c) {
  return __builtin_amdgcn_mfma_f32_16x16x32_bf16(a, b, c, 0, 0, 0);
}

static __device__ __forceinline__ float bf2f(uint16_t u) {
  union { uint32_t i; float f; } v; v.i = (uint32_t)u << 16; return v.f;
}

// ---------------- kernel 0: weights -> bf16 transposed; zero flags + ticket ---------
__global__ __launch_bounds__(256) void wt_kernel(const float* __restrict__ Wq,
                                                 const float* __restrict__ Wk,
                                                 const float* __restrict__ Wv,
                                                 bf16_t* __restrict__ Wt,
                                                 int* __restrict__ F) {
  int gid = blockIdx.x * 256 + threadIdx.x;  // 0 .. 196607
  if (gid <= 512) F[gid] = 0;                // 512 flags + 1 ticket, re-zeroed
  int proj = gid >> 16;
  int rem = gid & 65535;
  int k = rem >> 6, n = rem & 63;
  const float* W = (proj == 0) ? Wq : (proj == 1) ? Wk : Wv;
  float v = W[rem];
  if (proj == 0) v *= 0.125f;
  Wt[proj * 65536 + n * 1024 + k] = (bf16_t)v;
}

// ---------------- fused kernel: proj producers + attn consumers ---------------------
// grid 768 x 512thr. Role by TICKET (atomic counter): first 512 scheduled blocks are
// proj producers (pid = order; computes rows [16pid,16pid+16) of Q,K,V; releases
// F[pid]), rest are attn consumers (r6 QBLK=32 KV-split; waits on the flags its KV
// tiles need; 3-round tree merge in Psm). Producers never wait -> deadlock-free.
__global__ __launch_bounds__(512) void fused_kernel(
    const float* __restrict__ Xq, const float* __restrict__ Xk, const float* __restrict__ Xv,
    const bf16_t* __restrict__ Wt,
    bf16_t* __restrict__ Qb, bf16_t* __restrict__ Kb, bf16_t* __restrict__ Vt,
    float* __restrict__ Out, int* __restrict__ F) {
  __shared__ union {
    struct { char Xl[32768]; bf16_t Msm[8][16][64]; } pj;                 // 48 KB
    struct { char Psm[32768]; float mlA[4][32]; float mlB[4][32]; } at;   // 33 KB
  } sm;
  __shared__ int s_order;

  int tid = threadIdx.x;
  int w = tid >> 6, lane = tid & 63;
  int l15 = lane & 15, g = lane >> 4;

  if (tid == 0)
    s_order = __hip_atomic_fetch_add(F + 512, 1, __ATOMIC_RELAXED, __HIP_MEMORY_SCOPE_AGENT);
  __syncthreads();
  int order = s_order;

  if (order < 512) {
    // ================= proj role =================
    int pid = order;                 // row-group j = pid
    char* myx = sm.pj.Xl + w * 4096;
    int kw = w;

    bf16x8 Wf[4][4];
    auto loadW = [&](int p) {
      asm volatile("s_waitcnt lgkmcnt(0)" ::: "memory");   // prior ds_reads drained
      const char* wb = (const char*)Wt + (size_t)p * 131072 + (size_t)kw * 256;
#pragma unroll
      for (int ct = 0; ct < 4; ++ct) {
#pragma unroll
        for (int i = 0; i < 4; ++i) {
          int n = i * 4 + (lane >> 4);
          int srcb = ((lane & 15) * 16) ^ ((n & 7) << 4);
          __builtin_amdgcn_global_load_lds(
              (const __attribute__((address_space(1))) uint32_t*)(wb + (size_t)(ct * 16 + n) * 2048 + srcb),
              (__attribute__((address_space(3))) uint32_t*)(myx + i * 1024), 16, 0, 0);
        }
        asm volatile("s_waitcnt vmcnt(0)" ::: "memory");
        __builtin_amdgcn_sched_barrier(0);
#pragma unroll
        for (int s2 = 0; s2 < 4; ++s2)
          Wf[ct][s2] = *(const bf16x8*)(myx + l15 * 256 + ((s2 * 64 + g * 16) ^ ((l15 & 7) << 4)));
        asm volatile("s_waitcnt lgkmcnt(0)" ::: "memory");
        __builtin_amdgcn_sched_barrier(0);
      }
    };

    f32x4 acc[4] = {};
    float4 xA[4], xB[4];

    auto issueX = [&](int t, int sub, float4* xr) {
      int p = t >> 9, lt = t & 511;
      const float* X = (p == 0) ? Xq : (p == 1) ? Xk : Xv;
      const float* base = X + (size_t)lt * 16384 + kw * 128 + sub * 64 + (lane & 15) * 4;
#pragma unroll
      for (int i = 0; i < 4; ++i)
        xr[i] = *(const float4*)(base + ((lane >> 4) + 4 * i) * 1024);
    };

    auto writeX = [&](const float4* xr, int sub) {
      char* buf = myx + sub * 2048;
#pragma unroll
      for (int i = 0; i < 4; ++i) {
        int rw = (lane >> 4) + 4 * i;
        bf16_t t4[4] = {(bf16_t)xr[i].x, (bf16_t)xr[i].y, (bf16_t)xr[i].z, (bf16_t)xr[i].w};
        *(uint2*)(buf + rw * 128 + (((lane & 15) * 8) ^ ((rw & 7) << 4))) = *(const uint2*)t4;
      }
      asm volatile("s_waitcnt lgkmcnt(0)" ::: "memory");
      __builtin_amdgcn_sched_barrier(0);
    };

    auto computeX = [&](int sub) {
      const char* buf = myx + sub * 2048;
#pragma unroll
      for (int ks = 0; ks < 2; ++ks) {
        bf16x8 af = *(const bf16x8*)(buf + l15 * 128 + ((ks * 64 + g * 16) ^ ((l15 & 7) << 4)));
#pragma unroll
        for (int ct = 0; ct < 4; ++ct)
          acc[ct] = mfma16(af, Wf[ct][sub * 2 + ks], acc[ct]);
      }
    };

    loadW(0);
    issueX(pid, 0, xA);

#pragma unroll 1
    for (int T = 0; T < 3; ++T) {
      int t = T * 512 + pid;
      int p = T, lt = pid;
      if (T > 0) loadW(p);
      issueX(t, 1, xB);
      writeX(xA, 0);
      computeX(0);
      if (T < 2) issueX(t + 512, 0, xA);
      writeX(xB, 1);
      computeX(1);

      // ---- 8-way k-merge + output ----
#pragma unroll
      for (int ct = 0; ct < 4; ++ct)
#pragma unroll
        for (int r = 0; r < 4; ++r)
          sm.pj.Msm[w][g * 4 + r][ct * 16 + l15] = (bf16_t)acc[ct][r];
#pragma unroll
      for (int ct = 0; ct < 4; ++ct) acc[ct] = (f32x4){0.f, 0.f, 0.f, 0.f};
      __syncthreads();

      int row = tid >> 5, c0 = (tid & 31) * 2;
      float s0 = 0.f, s1 = 0.f;
#pragma unroll
      for (int w2 = 0; w2 < 8; ++w2) {
        uint32_t u = *(const uint32_t*)&sm.pj.Msm[w2][row][c0];
        s0 += bf2f((uint16_t)u);
        s1 += bf2f((uint16_t)(u >> 16));
      }

      if (p < 2) {
        bf16_t* Ob = (p == 0) ? Qb : Kb;
        bf16_t o2[2] = {(bf16_t)s0, (bf16_t)s1};
        *(uint32_t*)&Ob[(size_t)(lt * 16 + row) * 64 + c0] = *(const uint32_t*)o2;
        __syncthreads();
      } else {
        __syncthreads();
        bf16_t* Vsm = (bf16_t*)&sm.pj.Msm[0][0][0];  // [16 s][64 d], stride 72
        bf16_t o2[2] = {(bf16_t)s0, (bf16_t)s1};
        *(uint32_t*)&Vsm[row * 72 + c0] = *(const uint32_t*)o2;
        __syncthreads();
        if (tid < 128) {
          int d = tid >> 1, h = tid & 1;
          int bb = lt >> 7;
          int s_ = (lt & 127) * 16 + h * 8;
          bf16_t tmp[8];
#pragma unroll
          for (int i = 0; i < 8; ++i) tmp[i] = Vsm[(h * 8 + i) * 72 + d];
          *(uint4*)(Vt + ((size_t)(bb * 64 + d)) * 2048 + s_) = *(const uint4*)tmp;
        }
        __syncthreads();
      }
    }

    // ---- signal: rows [16*pid, 16*pid+16) of Q, K, V all written ----
    __threadfence();
    __syncthreads();
    if (tid == 0)
      __hip_atomic_store(F + pid, 1, __ATOMIC_RELEASE, __HIP_MEMORY_SCOPE_AGENT);
    return;
  }

  // ================= attn role =================
  int a = order - 512;              // 0..255
  int b = a >> 6;
  int x = a & 63;
  int qt = (b >= 2) ? (63 - x) : x; // pair heavy+light
  int q0 = qt * 32;
  char* Pw = sm.at.Psm + w * 4096;
  int gbase = b * 128;

  auto waitF = [&](int idx) {       // ALL lanes spin (same dword -> broadcast)
    int guard = 0;
    while (__hip_atomic_load(F + idx, __ATOMIC_ACQUIRE, __HIP_MEMORY_SCOPE_AGENT) == 0) {
      __builtin_amdgcn_s_sleep(2);
      if (++guard > (1 << 19)) break;
    }
    __builtin_amdgcn_sched_barrier(0);
  };

  // Q rows [q0, q0+32) = groups 2qt, 2qt+1
  waitF(gbase + 2 * qt);
  waitF(gbase + 2 * qt + 1);

  bf16x8 qf[2][2];
#pragma unroll
  for (int h = 0; h < 2; ++h) {
    size_t qrow = (size_t)(b * 2048 + q0 + h * 16 + l15) * 64;
    qf[h][0] = *(const bf16x8*)(Qb + qrow + g * 8);
    qf[h][1] = *(const bf16x8*)(Qb + qrow + 32 + g * 8);
  }

  float m_run[2][4], l_run[2][4];
  f32x4 acc_o[2][4] = {};
#pragma unroll
  for (int h = 0; h < 2; ++h)
#pragma unroll
    for (int r = 0; r < 4; ++r) { m_run[h][r] = -1e30f; l_run[h][r] = 0.f; }

  int ntiles = (q0 + 95) >> 6;
  const bf16_t* kbase = Kb + (size_t)b * 2048 * 64;
  const bf16_t* vbase = Vt + (size_t)b * 64 * 2048;

  for (int t = w; t < ntiles; t += 8) {
    int kv0 = t * 64;
    // wait for the K/V groups this tile reads (only up to the causal limit;
    // rows past it are masked, and 0xAA poison is a tiny finite bf16 -> safe)
    int fe = 4 * t + 3; if (fe > 2 * qt + 1) fe = 2 * qt + 1;
    for (int f2 = 4 * t; f2 <= fe; ++f2) waitF(gbase + f2);

    f32x4 s[2][4] = {};
#pragma unroll
    for (int ct = 0; ct < 4; ++ct) {
      const bf16_t* kr = kbase + (size_t)(kv0 + ct * 16 + l15) * 64 + g * 8;
      bf16x8 kf0 = *(const bf16x8*)kr;
      bf16x8 kf1 = *(const bf16x8*)(kr + 32);
#pragma unroll
      for (int h = 0; h < 2; ++h) {
        s[h][ct] = mfma16(qf[h][0], kf0, s[h][ct]);
        s[h][ct] = mfma16(qf[h][1], kf1, s[h][ct]);
      }
    }
    if (t == ntiles - 1) {
#pragma unroll
      for (int h = 0; h < 2; ++h)
#pragma unroll
        for (int ct = 0; ct < 4; ++ct)
#pragma unroll
          for (int r = 0; r < 4; ++r) {
            int kg_ = kv0 + ct * 16 + l15;
            int qg_ = q0 + h * 16 + g * 4 + r;
            if (kg_ > qg_) s[h][ct][r] = -1e30f;
          }
    }

#pragma unroll
    for (int h = 0; h < 2; ++h)
#pragma unroll
      for (int r = 0; r < 4; ++r) {
        float mx = fmaxf(fmaxf(s[h][0][r], s[h][1][r]), fmaxf(s[h][2][r], s[h][3][r]));
        mx = fmaxf(mx, __shfl_xor(mx, 1, 64));
        mx = fmaxf(mx, __shfl_xor(mx, 2, 64));
        mx = fmaxf(mx, __shfl_xor(mx, 4, 64));
        mx = fmaxf(mx, __shfl_xor(mx, 8, 64));
        float mnew = fmaxf(m_run[h][r], mx);
        float scale = exp2f((m_run[h][r] - mnew) * L2E);
        m_run[h][r] = mnew;
        float ps = 0.f;
        int qrl = h * 16 + g * 4 + r;
        char* pb = Pw + qrl * 128;
        int swp = (qrl & 7) << 4;
#pragma unroll
        for (int ct = 0; ct < 4; ++ct) {
          float p = exp2f((s[h][ct][r] - mnew) * L2E);
          ps += p;
          *(bf16_t*)(pb + ((ct * 32 + l15 * 2) ^ swp)) = (bf16_t)p;
        }
        ps += __shfl_xor(ps, 1, 64);
        ps += __shfl_xor(ps, 2, 64);
        ps += __shfl_xor(ps, 4, 64);
        ps += __shfl_xor(ps, 8, 64);
        l_run[h][r] = l_run[h][r] * scale + ps;
#pragma unroll
        for (int dt = 0; dt < 4; ++dt) acc_o[h][dt][r] *= scale;
      }

    int swpr = (l15 & 7) << 4;
#pragma unroll
    for (int ks = 0; ks < 2; ++ks) {
      bf16x8 pf0 = *(const bf16x8*)(Pw + l15 * 128 + ((ks * 64 + g * 16) ^ swpr));
      bf16x8 pf1 = *(const bf16x8*)(Pw + (16 + l15) * 128 + ((ks * 64 + g * 16) ^ swpr));
#pragma unroll
      for (int dt = 0; dt < 4; ++dt) {
        const bf16_t* vr = vbase + (size_t)(dt * 16 + l15) * 2048 + kv0 + ks * 32 + g * 8;
        bf16x8 vf = *(const bf16x8*)vr;
        acc_o[0][dt] = mfma16(pf0, vf, acc_o[0][dt]);
        acc_o[1][dt] = mfma16(pf1, vf, acc_o[1][dt]);
      }
    }
  }

  // ---- 3-round tree merge of the 8 per-wave partial states (reuses Psm) ----
  auto dump = [&](int slot) {
    float* buf = (float*)(sm.at.Psm + slot * 8192);
#pragma unroll
    for (int h = 0; h < 2; ++h)
#pragma unroll
      for (int dt = 0; dt < 4; ++dt)
#pragma unroll
        for (int r = 0; r < 4; ++r)
          buf[(h * 16 + g * 4 + r) * 64 + dt * 16 + l15] = acc_o[h][dt][r];
    if (l15 == 0) {
#pragma unroll
      for (int h = 0; h < 2; ++h)
#pragma unroll
        for (int r = 0; r < 4; ++r) {
          sm.at.mlA[slot][h * 16 + g * 4 + r] = m_run[h][r];
          sm.at.mlB[slot][h * 16 + g * 4 + r] = l_run[h][r];
        }
    }
  };
  auto mergeS = [&](int slot) {
    const float* buf = (const float*)(sm.at.Psm + slot * 8192);
#pragma unroll
    for (int h = 0; h < 2; ++h)
#pragma unroll
      for (int r = 0; r < 4; ++r) {
        int row = h * 16 + g * 4 + r;
        float mp = sm.at.mlA[slot][row], lp = sm.at.mlB[slot][row];
        float mn = fmaxf(m_run[h][r], mp);
        float ss = exp2f((m_run[h][r] - mn) * L2E);
        float sp = exp2f((mp - mn) * L2E);
        m_run[h][r] = mn;
        l_run[h][r] = l_run[h][r] * ss + lp * sp;
#pragma unroll
        for (int dt = 0; dt < 4; ++dt)
          acc_o[h][dt][r] = acc_o[h][dt][r] * ss + buf[row * 64 + dt * 16 + l15] * sp;
      }
  };

  __syncthreads();
  if (w >= 4) dump(w - 4);
  __syncthreads();
  if (w < 4) mergeS(w);
  __syncthreads();
  if (w == 2 || w == 3) dump(w - 2);
  __syncthreads();
  if (w < 2) mergeS(w);
  __syncthreads();
  if (w == 1) dump(0);
  __syncthreads();
  if (w == 0) {
    mergeS(0);
#pragma unroll
    for (int h = 0; h < 2; ++h)
#pragma unroll
      for (int r = 0; r < 4; ++r) {
        float inv = 1.0f / l_run[h][r];
        int row = h * 16 + g * 4 + r;
        size_t ob = (size_t)(b * 2048 + q0 + row) * 64 + l15;
#pragma unroll
        for (int dt = 0; dt < 4; ++dt)
          Out[ob + dt * 16] = acc_o[h][dt][r] * inv;
      }
  }
}

extern "C" void kernel_launch(void* const* d_in, const int* in_sizes, int n_in,
                              void* d_out, int out_size, void* d_ws, size_t ws_size,
                              hipStream_t stream) {
  const float* Xk = (const float*)d_in[0];
  const float* Xv = (const float*)d_in[1];
  const float* Xq = (const float*)d_in[2];
  const float* Wq = (const float*)d_in[3];
  const float* Wk = (const float*)d_in[4];
  const float* Wv = (const float*)d_in[5];
  float* Out = (float*)d_out;

  bf16_t* ws = (bf16_t*)d_ws;
  bf16_t* Qb = ws;                 // [8192][64]   bf16, pre-scaled by 0.125
  bf16_t* Kb = ws + 524288;        // [8192][64]   bf16
  bf16_t* Vt = ws + 1048576;       // [4][64][2048] bf16 (V transposed)
  bf16_t* Wt = ws + 1572864;       // [3][64][1024] bf16 (weights transposed)
  int* F = (int*)((char*)d_ws + 4 * 1024 * 1024);   // 512 flags + 1 ticket

  wt_kernel<<<dim3(768), dim3(256), 0, stream>>>(Wq, Wk, Wv, Wt, F);
  fused_kernel<<<dim3(768), dim3(512), 0, stream>>>(Xq, Xk, Xv, Wt, Qb, Kb, Vt, Out, F);
}